// Round 1
// baseline (284.900 us; speedup 1.0000x reference)
//
#include <hip/hip_runtime.h>

#define IMG 1024

// entropy of a window sum s with n = 1/inv_n elements: -(p0*log2 p0 + p1*log2 p1)
__device__ __forceinline__ float ent(float s, float inv_n) {
    float p1 = s * inv_n;
    float p0 = 1.0f - p1;
    float l1 = (p1 > 0.0f) ? __log2f(p1) : 0.0f;
    float l0 = (p0 > 0.0f) ? __log2f(p0) : 0.0f;
    return -(p0 * l0 + p1 * l1);
}

__device__ __forceinline__ float wave_sum(float v) {
#pragma unroll
    for (int off = 32; off > 0; off >>= 1)
        v += __shfl_down(v, off);   // width = wave = 64
    return v;
}

// Kernel 1: per 64x64 tile, levels k=2..64. Grid = 32 images * 256 tiles.
__global__ __launch_bounds__(256) void slice_k1(const float* __restrict__ x,
                                                float* __restrict__ out,
                                                float* __restrict__ ws) {
    const int b    = blockIdx.x >> 8;    // image
    const int tile = blockIdx.x & 255;   // 16x16 tiles of 64x64
    const int tr = tile >> 4, tc = tile & 15;
    const int t = threadIdx.x;
    const int r2 = t >> 4, c2 = t & 15;  // this thread's 4x4 patch in the tile

    const float* p = x + (size_t)b * (IMG * IMG)
                       + (size_t)(tr * 64 + r2 * 4) * IMG + (tc * 64 + c2 * 4);
    float4 v0 = *(const float4*)(p);
    float4 v1 = *(const float4*)(p + IMG);
    float4 v2 = *(const float4*)(p + 2 * IMG);
    float4 v3 = *(const float4*)(p + 3 * IMG);

    // level 1 (k=2): four 2x2 sums
    float s1a = v0.x + v0.y + v1.x + v1.y;
    float s1b = v0.z + v0.w + v1.z + v1.w;
    float s1c = v2.x + v2.y + v3.x + v3.y;
    float s1d = v2.z + v2.w + v3.z + v3.w;
    float e1 = ent(s1a, 0.25f) + ent(s1b, 0.25f) + ent(s1c, 0.25f) + ent(s1d, 0.25f);
    // level 2 (k=4)
    float s2 = s1a + s1b + s1c + s1d;
    float e2 = ent(s2, 1.0f / 16.0f);

    __shared__ float l2[256];  // 16x16
    __shared__ float l3[64];   // 8x8
    __shared__ float l4[16];   // 4x4
    __shared__ float l5[4];    // 2x2
    __shared__ float wred[2][4];

    l2[t] = s2;
    __syncthreads();

    float e3 = 0.0f, e4 = 0.0f, e5 = 0.0f;
    if (t < 64) {  // level 3 (k=8): 8x8
        int r = t >> 3, c = t & 7;
        float s3 = l2[(2 * r) * 16 + 2 * c] + l2[(2 * r) * 16 + 2 * c + 1]
                 + l2[(2 * r + 1) * 16 + 2 * c] + l2[(2 * r + 1) * 16 + 2 * c + 1];
        e3 = ent(s3, 1.0f / 64.0f);
        l3[t] = s3;
    }
    __syncthreads();
    if (t < 16) {  // level 4 (k=16): 4x4
        int r = t >> 2, c = t & 3;
        float s4 = l3[(2 * r) * 8 + 2 * c] + l3[(2 * r) * 8 + 2 * c + 1]
                 + l3[(2 * r + 1) * 8 + 2 * c] + l3[(2 * r + 1) * 8 + 2 * c + 1];
        e4 = ent(s4, 1.0f / 256.0f);
        l4[t] = s4;
    }
    __syncthreads();
    if (t < 4) {   // level 5 (k=32): 2x2
        int r = t >> 1, c = t & 1;
        float s5 = l4[(2 * r) * 4 + 2 * c] + l4[(2 * r) * 4 + 2 * c + 1]
                 + l4[(2 * r + 1) * 4 + 2 * c] + l4[(2 * r + 1) * 4 + 2 * c + 1];
        e5 = ent(s5, 1.0f / 1024.0f);
        l5[t] = s5;
    }
    __syncthreads();
    float e6 = 0.0f;
    if (t == 0) {  // level 6 (k=64): whole tile
        float s6 = l5[0] + l5[1] + l5[2] + l5[3];
        e6 = ent(s6, 1.0f / 4096.0f);
        ws[b * 256 + tr * 16 + tc] = s6;  // per-image 16x16 level-6 grid
    }

    // block-reduce e1,e2 (all waves); e3..e5 live entirely in wave 0
    float r1  = wave_sum(e1);
    float r2p = wave_sum(e2);
    int wave = t >> 6, lane = t & 63;
    if (lane == 0) { wred[0][wave] = r1; wred[1][wave] = r2p; }
    float r3 = wave_sum(e3);  // waves 1..3 reduce zeros
    float r4 = wave_sum(e4);
    float r5 = wave_sum(e5);
    __syncthreads();
    if (t == 0) {
        float t1 = wred[0][0] + wred[0][1] + wred[0][2] + wred[0][3];
        float t2 = wred[1][0] + wred[1][1] + wred[1][2] + wred[1][3];
        float* o = out + b * 8;
        atomicAdd(o + 0, t1 * (1.0f / 262144.0f));  // k=2:   512^2 windows
        atomicAdd(o + 1, t2 * (1.0f / 65536.0f));   // k=4:   256^2
        atomicAdd(o + 2, r3 * (1.0f / 16384.0f));   // k=8:   128^2
        atomicAdd(o + 3, r4 * (1.0f / 4096.0f));    // k=16:  64^2
        atomicAdd(o + 4, r5 * (1.0f / 1024.0f));    // k=32:  32^2
        atomicAdd(o + 5, e6 * (1.0f / 256.0f));     // k=64:  16^2
    }
}

// Kernel 2: k=128, k=256 from the 16x16 level-6 grid. Grid = 32, one wave each.
__global__ __launch_bounds__(64) void slice_k2(const float* __restrict__ ws,
                                               float* __restrict__ out) {
    const int b = blockIdx.x;
    const int t = threadIdx.x;
    __shared__ float l6[256];
    __shared__ float l7[64];
    const float* p = ws + b * 256;
#pragma unroll
    for (int j = 0; j < 4; ++j) l6[t + 64 * j] = p[t + 64 * j];
    __syncthreads();
    int r = t >> 3, c = t & 7;  // level 7 (k=128): 8x8
    float s7 = l6[(2 * r) * 16 + 2 * c] + l6[(2 * r) * 16 + 2 * c + 1]
             + l6[(2 * r + 1) * 16 + 2 * c] + l6[(2 * r + 1) * 16 + 2 * c + 1];
    float e7 = ent(s7, 1.0f / 16384.0f);
    l7[t] = s7;
    __syncthreads();
    float e8 = 0.0f;
    if (t < 16) {  // level 8 (k=256): 4x4
        int r8 = t >> 2, c8 = t & 3;
        float s8 = l7[(2 * r8) * 8 + 2 * c8] + l7[(2 * r8) * 8 + 2 * c8 + 1]
                 + l7[(2 * r8 + 1) * 8 + 2 * c8] + l7[(2 * r8 + 1) * 8 + 2 * c8 + 1];
        e8 = ent(s8, 1.0f / 65536.0f);
    }
    float t7 = wave_sum(e7);
    float t8 = wave_sum(e8);
    if (t == 0) {
        out[b * 8 + 6] = t7 * (1.0f / 64.0f);  // k=128: 8^2 windows
        out[b * 8 + 7] = t8 * (1.0f / 16.0f);  // k=256: 4^2
    }
}

extern "C" void kernel_launch(void* const* d_in, const int* in_sizes, int n_in,
                              void* d_out, int out_size, void* d_ws, size_t ws_size,
                              hipStream_t stream) {
    const float* x = (const float*)d_in[0];
    float* out = (float*)d_out;
    float* ws  = (float*)d_ws;

    // harness poisons d_out with 0xAA; we accumulate via atomics, so zero it
    hipMemsetAsync(out, 0, (size_t)out_size * sizeof(float), stream);

    slice_k1<<<32 * 256, 256, 0, stream>>>(x, out, ws);
    slice_k2<<<32, 64, 0, stream>>>(ws, out);
}

// Round 2
// 184.591 us; speedup vs baseline: 1.5434x; 1.5434x over previous
//
#include <hip/hip_runtime.h>

#define IMG 1024

// entropy of a window sum s with n = 1/inv_n elements: -(p0*log2 p0 + p1*log2 p1)
__device__ __forceinline__ float ent(float s, float inv_n) {
    float p1 = s * inv_n;
    float p0 = 1.0f - p1;
    float l1 = (p1 > 0.0f) ? __log2f(p1) : 0.0f;
    float l0 = (p0 > 0.0f) ? __log2f(p0) : 0.0f;
    return -(p0 * l0 + p1 * l1);
}

__device__ __forceinline__ float bfly_sum(float v) {
#pragma unroll
    for (int m = 32; m >= 1; m >>= 1) v += __shfl_xor(v, m);
    return v;  // full 64-lane sum, broadcast to all lanes
}

// Kernel 1: one 128x128 tile per block; levels k=2..128.
// Thread = 8x8 patch (regs); wave = 64x64 region (shfl_xor); block = 128x128.
// Lane layout within wave: lane = cy*8 + cx (row-major 8x8) -> x bits {0,1,2}, y bits {3,4,5}.
__global__ __launch_bounds__(256, 4) void slice_k1(const float* __restrict__ x,
                                                   float* __restrict__ ws) {
    const int b    = blockIdx.x >> 6;    // image
    const int tile = blockIdx.x & 63;    // 8x8 tiles of 128x128
    const int tr = tile >> 3, tc = tile & 7;
    const int t = threadIdx.x;
    const int w = t >> 6, lane = t & 63;
    const int wr = w >> 1, wc = w & 1;   // 2x2 waves of 64x64
    const int cy = lane >> 3, cx = lane & 7;

    const int row0 = tr * 128 + wr * 64 + cy * 8;
    const int col0 = tc * 128 + wc * 64 + cx * 8;
    const float* p = x + (size_t)b * (IMG * IMG) + (size_t)row0 * IMG + col0;

    // 16 independent loads, all issued before any use
    float4 va[8], vb[8];
#pragma unroll
    for (int i = 0; i < 8; ++i) {
        va[i] = *(const float4*)(p + (size_t)i * IMG);
        vb[i] = *(const float4*)(p + (size_t)i * IMG + 4);
    }

    // k=2 (16 windows) and k=4 partial sums, in registers
    float e2sum = 0.f, e4sum = 0.f;
    float s4[2][2] = {{0.f, 0.f}, {0.f, 0.f}};
#pragma unroll
    for (int ry = 0; ry < 4; ++ry) {
        float4 a0 = va[2 * ry], a1 = va[2 * ry + 1];
        float4 b0 = vb[2 * ry], b1 = vb[2 * ry + 1];
        float sA = a0.x + a0.y + a1.x + a1.y;
        float sB = a0.z + a0.w + a1.z + a1.w;
        float sC = b0.x + b0.y + b1.x + b1.y;
        float sD = b0.z + b0.w + b1.z + b1.w;
        e2sum += ent(sA, 0.25f) + ent(sB, 0.25f) + ent(sC, 0.25f) + ent(sD, 0.25f);
        s4[ry >> 1][0] += sA + sB;
        s4[ry >> 1][1] += sC + sD;
    }
    float s8 = 0.f;
#pragma unroll
    for (int i = 0; i < 2; ++i)
#pragma unroll
        for (int j = 0; j < 2; ++j) { e4sum += ent(s4[i][j], 1.f / 16.f); s8 += s4[i][j]; }
    float e8 = ent(s8, 1.f / 64.f);

    // k=16/32/64 via in-wave 2x2 merges (x-mask, then y-mask)
    float s16 = s8 + __shfl_xor(s8, 1);  s16 += __shfl_xor(s16, 8);
    float e16 = ent(s16, 1.f / 256.f);                 // uniform over xor{1,8} groups
    float s32 = s16 + __shfl_xor(s16, 2); s32 += __shfl_xor(s32, 16);
    float e32 = ent(s32, 1.f / 1024.f);                // uniform over xor{1,2,8,16}
    float s64 = s32 + __shfl_xor(s32, 4); s64 += __shfl_xor(s64, 32);
    float e64 = ent(s64, 1.f / 4096.f);                // uniform across wave

    // wave-level sums (each counts every distinct window exactly once)
    float E2 = bfly_sum(e2sum);   // 1024 k=2 windows per wave
    float E4 = bfly_sum(e4sum);   // 256
    float E8 = bfly_sum(e8);      // 64
    float E16 = e16 + __shfl_xor(e16, 2); E16 += __shfl_xor(E16, 4);
    E16 += __shfl_xor(E16, 16);   E16 += __shfl_xor(E16, 32);   // 16 distinct
    float E32 = e32 + __shfl_xor(e32, 4); E32 += __shfl_xor(E32, 32);  // 4 distinct

    __shared__ float wl[4][8];
    if (lane == 0) {
        wl[w][0] = E2;  wl[w][1] = E4;  wl[w][2] = E8;
        wl[w][3] = E16; wl[w][4] = E32; wl[w][5] = e64; wl[w][6] = s64;
    }
    __syncthreads();
    if (t < 8) {
        float r;
        if (t < 6) {
            r = wl[0][t] + wl[1][t] + wl[2][t] + wl[3][t];
        } else {
            float s128 = wl[0][6] + wl[1][6] + wl[2][6] + wl[3][6];
            r = (t == 6) ? ent(s128, 1.f / 16384.f) : s128;
        }
        ws[(size_t)blockIdx.x * 8 + t] = r;  // {E2,E4,E8,E16,E32,E64,e128,s128}
    }
}

// Kernel 2: final per-image reduction + k=256. One wave per image; plain stores.
// Lane l = block tile index within image (tr*8 + tc).
__global__ __launch_bounds__(64) void slice_k2(const float* __restrict__ ws,
                                               float* __restrict__ out) {
    const int b = blockIdx.x, l = threadIdx.x;
    const float4* g = (const float4*)(ws + ((size_t)b * 64 + l) * 8);
    float4 u0 = g[0], u1 = g[1];
    float v[8] = {u0.x, u0.y, u0.z, u0.w, u1.x, u1.y, u1.z, u1.w};

    // k=256 from per-block s128 (v[7]); x bit0 = lane bit0, y bit0 = lane bit3
    float s256 = v[7] + __shfl_xor(v[7], 1); s256 += __shfl_xor(s256, 8);
    float e256 = ent(s256, 1.f / 65536.f);
    float E256 = e256 + __shfl_xor(e256, 2); E256 += __shfl_xor(E256, 4);
    E256 += __shfl_xor(E256, 16);  E256 += __shfl_xor(E256, 32);  // 16 distinct

    float sums[7];
#pragma unroll
    for (int j = 0; j < 7; ++j) sums[j] = bfly_sum(v[j]);

    if (l == 0) {
        const float invw[7] = {1.f / 262144.f, 1.f / 65536.f, 1.f / 16384.f,
                               1.f / 4096.f,   1.f / 1024.f,  1.f / 256.f, 1.f / 64.f};
        float* o = out + b * 8;
#pragma unroll
        for (int j = 0; j < 7; ++j) o[j] = sums[j] * invw[j];
        o[7] = E256 * (1.f / 16.f);
    }
}

extern "C" void kernel_launch(void* const* d_in, const int* in_sizes, int n_in,
                              void* d_out, int out_size, void* d_ws, size_t ws_size,
                              hipStream_t stream) {
    const float* x = (const float*)d_in[0];
    float* out = (float*)d_out;
    float* ws  = (float*)d_ws;  // 2048 blocks * 8 floats = 64 KiB

    slice_k1<<<32 * 64, 256, 0, stream>>>(x, ws);
    slice_k2<<<32, 64, 0, stream>>>(ws, out);
}